// Round 1
// baseline (22988.782 us; speedup 1.0000x reference)
//
#include <hip/hip_runtime.h>
#include <math.h>

#define N_NODES 100000
#define N_EDGES 1600000
#define HDIM 64

// float atomic-min via int-min (v>=0) / uint-max (v<0); buffer pre-filled +inf.
__device__ __forceinline__ void atomicMinF(float* addr, float v) {
  if (v >= 0.0f) {
    atomicMin(reinterpret_cast<int*>(addr), __float_as_int(v));
  } else {
    atomicMax(reinterpret_cast<unsigned int*>(addr), __float_as_uint(v));
  }
}

__global__ __launch_bounds__(256) void fill_inf_kernel(float4* __restrict__ p, int n4) {
  int i = blockIdx.x * 256 + threadIdx.x;
  if (i < n4) p[i] = make_float4(INFINITY, INFINITY, INFINITY, INFINITY);
}

// h = x*emb_w + emb_b  (NF==1), then z = h @ W1a[0] + b1[0].
// 64 nodes/block, 4 threads/node, each thread owns 16 output columns.
__global__ __launch_bounds__(256) void k_embed_z(
    const float* __restrict__ x, const float* __restrict__ emb_w,
    const float* __restrict__ emb_b,
    const float* __restrict__ w1, const float* __restrict__ b1,
    float* __restrict__ h, float* __restrict__ z) {
  __shared__ float hs[64][65];
  const int t = threadIdx.x;
  const int nl = t >> 2;        // node within block
  const int l4 = t & 3;         // quarter
  const int i = blockIdx.x * 64 + nl;
  const bool valid = (i < N_NODES);
  const int jbase = l4 * 16;
  const float xv = valid ? x[i] : 0.0f;

  float hv[16];
  #pragma unroll
  for (int jj = 0; jj < 16; ++jj) {
    int j = jbase + jj;
    hv[jj] = fmaf(xv, emb_w[j], emb_b[j]);
    hs[nl][j] = hv[jj];
  }
  if (valid) {
    #pragma unroll
    for (int q = 0; q < 4; ++q)
      reinterpret_cast<float4*>(h + (size_t)i * HDIM)[l4 * 4 + q] =
          make_float4(hv[4*q], hv[4*q+1], hv[4*q+2], hv[4*q+3]);
  }
  __syncthreads();

  float acc[16];
  #pragma unroll
  for (int jj = 0; jj < 16; ++jj) acc[jj] = b1[jbase + jj];
  #pragma unroll 8
  for (int k = 0; k < 64; ++k) {
    float hk = hs[nl][k];
    const float* wr = w1 + k * 64 + jbase;
    #pragma unroll
    for (int jj = 0; jj < 16; ++jj) acc[jj] = fmaf(hk, wr[jj], acc[jj]);
  }
  if (valid) {
    #pragma unroll
    for (int q = 0; q < 4; ++q)
      reinterpret_cast<float4*>(z + (size_t)i * HDIM)[l4 * 4 + q] =
          make_float4(acc[4*q], acc[4*q+1], acc[4*q+2], acc[4*q+3]);
  }
}

// Per edge: hid = relu(z[src] + ea*w1b); m = hid @ W2 + b2; atomicMin into aggr[dst].
__global__ __launch_bounds__(256) void k_edge(
    const int* __restrict__ ei, const float* __restrict__ eattr,
    const float* __restrict__ z,
    const float* __restrict__ w1b, const float* __restrict__ w2,
    const float* __restrict__ b2,
    float* __restrict__ aggr) {
  const int e = blockIdx.x * 256 + threadIdx.x;
  if (e >= N_EDGES) return;
  const int src = ei[e];
  const int dst = ei[N_EDGES + e];
  const float ea = eattr[e];
  const float4* zr = reinterpret_cast<const float4*>(z + (size_t)src * HDIM);

  float hid[64];
  #pragma unroll
  for (int q = 0; q < 16; ++q) {
    float4 zv = zr[q];
    hid[4*q+0] = fmaxf(fmaf(ea, w1b[4*q+0], zv.x), 0.0f);
    hid[4*q+1] = fmaxf(fmaf(ea, w1b[4*q+1], zv.y), 0.0f);
    hid[4*q+2] = fmaxf(fmaf(ea, w1b[4*q+2], zv.z), 0.0f);
    hid[4*q+3] = fmaxf(fmaf(ea, w1b[4*q+3], zv.w), 0.0f);
  }

  float* ar = aggr + (size_t)dst * HDIM;
  for (int j8 = 0; j8 < 8; ++j8) {
    float acc[8];
    #pragma unroll
    for (int jj = 0; jj < 8; ++jj) acc[jj] = b2[j8 * 8 + jj];
    #pragma unroll
    for (int k = 0; k < 64; ++k) {
      float hk = hid[k];
      const float* wr = w2 + k * 64 + j8 * 8;   // wave-uniform -> s_load
      #pragma unroll
      for (int jj = 0; jj < 8; ++jj) acc[jj] = fmaf(hk, wr[jj], acc[jj]);
    }
    #pragma unroll
    for (int jj = 0; jj < 8; ++jj) atomicMinF(ar + j8 * 8 + jj, acc[jj]);
  }
}

// Per node: u=[h, fix(aggr)]; h1=relu(u@U1+b1); h_new=h1@U2+b2; then
// z_next = h_new @ W1a[l+1] + b1[l+1]  (or final fc for LAST).
template <int LAST>
__global__ __launch_bounds__(256) void k_update(
    const float* __restrict__ aggr,
    const float* __restrict__ u1w, const float* __restrict__ u1b,
    const float* __restrict__ u2w, const float* __restrict__ u2b,
    const float* __restrict__ w1next, const float* __restrict__ b1next,
    const float* __restrict__ fcw, const float* __restrict__ fcb,
    float* __restrict__ h, float* __restrict__ z, float* __restrict__ out) {
  __shared__ float us[64][129];
  __shared__ float h1s[64][65];
  const int t = threadIdx.x;
  const int nl = t >> 2;
  const int l4 = t & 3;
  const int i = blockIdx.x * 64 + nl;
  const bool valid = (i < N_NODES);
  const size_t off = (size_t)(valid ? i : 0) * HDIM;
  const int jbase = l4 * 16;

  #pragma unroll
  for (int q = 0; q < 4; ++q) {
    float4 hv = reinterpret_cast<const float4*>(h + off)[l4 * 4 + q];
    us[nl][jbase + 4*q + 0] = hv.x;
    us[nl][jbase + 4*q + 1] = hv.y;
    us[nl][jbase + 4*q + 2] = hv.z;
    us[nl][jbase + 4*q + 3] = hv.w;
    float4 av = reinterpret_cast<const float4*>(aggr + off)[l4 * 4 + q];
    av.x = isinf(av.x) ? 0.0f : av.x;
    av.y = isinf(av.y) ? 0.0f : av.y;
    av.z = isinf(av.z) ? 0.0f : av.z;
    av.w = isinf(av.w) ? 0.0f : av.w;
    us[nl][64 + jbase + 4*q + 0] = av.x;
    us[nl][64 + jbase + 4*q + 1] = av.y;
    us[nl][64 + jbase + 4*q + 2] = av.z;
    us[nl][64 + jbase + 4*q + 3] = av.w;
  }
  __syncthreads();

  float acc[16];
  #pragma unroll
  for (int jj = 0; jj < 16; ++jj) acc[jj] = u1b[jbase + jj];
  #pragma unroll 4
  for (int k = 0; k < 128; ++k) {
    float uk = us[nl][k];
    const float* wr = u1w + k * 64 + jbase;
    #pragma unroll
    for (int jj = 0; jj < 16; ++jj) acc[jj] = fmaf(uk, wr[jj], acc[jj]);
  }
  #pragma unroll
  for (int jj = 0; jj < 16; ++jj) h1s[nl][jbase + jj] = fmaxf(acc[jj], 0.0f);
  __syncthreads();

  float hn[16];
  #pragma unroll
  for (int jj = 0; jj < 16; ++jj) hn[jj] = u2b[jbase + jj];
  #pragma unroll 4
  for (int k = 0; k < 64; ++k) {
    float hk = h1s[nl][k];
    const float* wr = u2w + k * 64 + jbase;
    #pragma unroll
    for (int jj = 0; jj < 16; ++jj) hn[jj] = fmaf(hk, wr[jj], hn[jj]);
  }
  if (valid) {
    #pragma unroll
    for (int q = 0; q < 4; ++q)
      reinterpret_cast<float4*>(h + off)[l4 * 4 + q] =
          make_float4(hn[4*q], hn[4*q+1], hn[4*q+2], hn[4*q+3]);
  }

  if (LAST) {
    float s = 0.0f;
    #pragma unroll
    for (int jj = 0; jj < 16; ++jj) s = fmaf(hn[jj], fcw[jbase + jj], s);
    s += __shfl_xor(s, 1);
    s += __shfl_xor(s, 2);
    if (l4 == 0 && valid) out[i] = s + fcb[0];
  } else {
    __syncthreads();
    #pragma unroll
    for (int jj = 0; jj < 16; ++jj) h1s[nl][jbase + jj] = hn[jj];
    __syncthreads();
    float zz[16];
    #pragma unroll
    for (int jj = 0; jj < 16; ++jj) zz[jj] = b1next[jbase + jj];
    #pragma unroll 4
    for (int k = 0; k < 64; ++k) {
      float hk = h1s[nl][k];
      const float* wr = w1next + k * 64 + jbase;
      #pragma unroll
      for (int jj = 0; jj < 16; ++jj) zz[jj] = fmaf(hk, wr[jj], zz[jj]);
    }
    if (valid) {
      #pragma unroll
      for (int q = 0; q < 4; ++q)
        reinterpret_cast<float4*>(z + off)[l4 * 4 + q] =
            make_float4(zz[4*q], zz[4*q+1], zz[4*q+2], zz[4*q+3]);
    }
  }
}

extern "C" void kernel_launch(void* const* d_in, const int* in_sizes, int n_in,
                              void* d_out, int out_size, void* d_ws, size_t ws_size,
                              hipStream_t stream) {
  const float* x      = (const float*)d_in[0];
  const int*   ei     = (const int*)d_in[1];
  const float* eattr  = (const float*)d_in[2];
  const float* emb_w  = (const float*)d_in[3];
  const float* emb_b  = (const float*)d_in[4];
  const float* msg_w1 = (const float*)d_in[5];
  const float* msg_b1 = (const float*)d_in[6];
  const float* msg_w2 = (const float*)d_in[7];
  const float* msg_b2 = (const float*)d_in[8];
  const float* upd_w1 = (const float*)d_in[9];
  const float* upd_b1 = (const float*)d_in[10];
  const float* upd_w2 = (const float*)d_in[11];
  const float* upd_b2 = (const float*)d_in[12];
  const float* fc_w   = (const float*)d_in[13];
  const float* fc_b   = (const float*)d_in[14];
  float* out = (float*)d_out;

  float* h    = (float*)d_ws;                       // N*64 f32
  float* zbuf = h + (size_t)N_NODES * HDIM;         // N*64 f32
  float* aggr = zbuf + (size_t)N_NODES * HDIM;      // N*64 f32

  const int nodeBlocks = (N_NODES + 63) / 64;
  const int edgeBlocks = (N_EDGES + 255) / 256;
  const int fillBlocks = (N_NODES * HDIM / 4 + 255) / 256;

  k_embed_z<<<nodeBlocks, 256, 0, stream>>>(x, emb_w, emb_b, msg_w1, msg_b1, h, zbuf);

  for (int l = 0; l < 5; ++l) {
    fill_inf_kernel<<<fillBlocks, 256, 0, stream>>>((float4*)aggr, N_NODES * HDIM / 4);
    k_edge<<<edgeBlocks, 256, 0, stream>>>(
        ei, eattr, zbuf,
        msg_w1 + l * 65 * 64 + 64 * 64,   // w1b: row 64 (edge_attr coeffs)
        msg_w2 + l * 64 * 64,
        msg_b2 + l * 64,
        aggr);
    if (l < 4) {
      k_update<0><<<nodeBlocks, 256, 0, stream>>>(
          aggr,
          upd_w1 + l * 128 * 64, upd_b1 + l * 64,
          upd_w2 + l * 64 * 64,  upd_b2 + l * 64,
          msg_w1 + (l + 1) * 65 * 64, msg_b1 + (l + 1) * 64,
          nullptr, nullptr,
          h, zbuf, nullptr);
    } else {
      k_update<1><<<nodeBlocks, 256, 0, stream>>>(
          aggr,
          upd_w1 + l * 128 * 64, upd_b1 + l * 64,
          upd_w2 + l * 64 * 64,  upd_b2 + l * 64,
          nullptr, nullptr,
          fc_w, fc_b,
          h, zbuf, out);
    }
  }
}

// Round 2
// 4669.850 us; speedup vs baseline: 4.9228x; 4.9228x over previous
//
#include <hip/hip_runtime.h>
#include <math.h>

#define N_NODES 100000
#define N_EDGES 1600000
#define HDIM 64
#define NBUCK 64
#define SCAN_T 1024
#define SCAN_CHUNK 98   // ceil(100000/1024)

// ---------------- CSR build ----------------

__global__ __launch_bounds__(256) void k_zero_int(int* __restrict__ p, int n) {
  int i = blockIdx.x * 256 + threadIdx.x;
  if (i < n) p[i] = 0;
}

__global__ __launch_bounds__(256) void k_deg_count(const int* __restrict__ ei,
                                                   int* __restrict__ deg) {
  int e = blockIdx.x * 256 + threadIdx.x;
  if (e < N_EDGES) atomicAdd(&deg[ei[N_EDGES + e]], 1);
}

// single-block exclusive scan of deg[N] -> row_ptr[N+1]
__global__ __launch_bounds__(SCAN_T) void k_rowptr(const int* __restrict__ deg,
                                                   int* __restrict__ row_ptr) {
  __shared__ int sums[SCAN_T];
  const int t = threadIdx.x;
  const int lo = t * SCAN_CHUNK;
  const int hi = min(lo + SCAN_CHUNK, N_NODES);
  int s = 0;
  for (int i = lo; i < hi; ++i) s += deg[i];
  sums[t] = s;
  __syncthreads();
  for (int off = 1; off < SCAN_T; off <<= 1) {
    int v = (t >= off) ? sums[t - off] : 0;
    __syncthreads();
    sums[t] += v;
    __syncthreads();
  }
  int run = (t == 0) ? 0 : sums[t - 1];
  for (int i = lo; i < hi; ++i) { row_ptr[i] = run; run += deg[i]; }
  if (t == SCAN_T - 1) row_ptr[N_NODES] = run;
}

__global__ __launch_bounds__(256) void k_scatter(
    const int* __restrict__ ei, const float* __restrict__ eattr,
    const int* __restrict__ row_ptr, int* __restrict__ cursor,
    int* __restrict__ s_src, float* __restrict__ s_ea) {
  int e = blockIdx.x * 256 + threadIdx.x;
  if (e >= N_EDGES) return;
  int d = ei[N_EDGES + e];
  int pos = row_ptr[d] + atomicAdd(&cursor[d], 1);
  s_src[pos] = ei[e];
  s_ea[pos] = eattr[e];
}

__global__ __launch_bounds__(256) void k_bucket_hist(const int* __restrict__ deg,
                                                     int* __restrict__ bhist) {
  int i = blockIdx.x * 256 + threadIdx.x;
  if (i < N_NODES) atomicAdd(&bhist[min(deg[i], NBUCK - 1)], 1);
}

__global__ __launch_bounds__(64) void k_bucket_scan(const int* __restrict__ bhist,
                                                    int* __restrict__ bcursor) {
  if (threadIdx.x == 0) {
    int run = 0;
    for (int b = 0; b < NBUCK; ++b) { bcursor[b] = run; run += bhist[b]; }
  }
}

__global__ __launch_bounds__(256) void k_bucket_scatter(const int* __restrict__ deg,
                                                        int* __restrict__ bcursor,
                                                        int* __restrict__ node_order) {
  __shared__ int lhist[NBUCK];
  __shared__ int lbase[NBUCK];
  __shared__ int lcur[NBUCK];
  const int t = threadIdx.x;
  const int i = blockIdx.x * 256 + t;
  if (t < NBUCK) { lhist[t] = 0; lcur[t] = 0; }
  __syncthreads();
  int b = -1;
  if (i < N_NODES) { b = min(deg[i], NBUCK - 1); atomicAdd(&lhist[b], 1); }
  __syncthreads();
  if (t < NBUCK && lhist[t] > 0) lbase[t] = atomicAdd(&bcursor[t], lhist[t]);
  __syncthreads();
  if (i < N_NODES) {
    int r = atomicAdd(&lcur[b], 1);
    node_order[lbase[b] + r] = i;
  }
}

// ---------------- per-layer kernels ----------------

// h = x*emb_w + emb_b (NF==1), then z = h @ W1a[0] + b1[0].
__global__ __launch_bounds__(256) void k_embed_z(
    const float* __restrict__ x, const float* __restrict__ emb_w,
    const float* __restrict__ emb_b,
    const float* __restrict__ w1, const float* __restrict__ b1,
    float* __restrict__ h, float* __restrict__ z) {
  __shared__ float hs[64][65];
  const int t = threadIdx.x;
  const int nl = t >> 2;
  const int l4 = t & 3;
  const int i = blockIdx.x * 64 + nl;
  const bool valid = (i < N_NODES);
  const int jbase = l4 * 16;
  const float xv = valid ? x[i] : 0.0f;

  float hv[16];
  #pragma unroll
  for (int jj = 0; jj < 16; ++jj) {
    int j = jbase + jj;
    hv[jj] = fmaf(xv, emb_w[j], emb_b[j]);
    hs[nl][j] = hv[jj];
  }
  if (valid) {
    #pragma unroll
    for (int q = 0; q < 4; ++q)
      reinterpret_cast<float4*>(h + (size_t)i * HDIM)[l4 * 4 + q] =
          make_float4(hv[4*q], hv[4*q+1], hv[4*q+2], hv[4*q+3]);
  }
  __syncthreads();

  float acc[16];
  #pragma unroll
  for (int jj = 0; jj < 16; ++jj) acc[jj] = b1[jbase + jj];
  #pragma unroll 8
  for (int k = 0; k < 64; ++k) {
    float hk = hs[nl][k];
    const float* wr = w1 + k * 64 + jbase;
    #pragma unroll
    for (int jj = 0; jj < 16; ++jj) acc[jj] = fmaf(hk, wr[jj], acc[jj]);
  }
  if (valid) {
    #pragma unroll
    for (int q = 0; q < 4; ++q)
      reinterpret_cast<float4*>(z + (size_t)i * HDIM)[l4 * 4 + q] =
          make_float4(acc[4*q], acc[4*q+1], acc[4*q+2], acc[4*q+3]);
  }
}

// One thread per node (degree-sorted order): walk CSR segment, compute message
// inline, register min-reduce. hid_k computed on the fly; W2/b2 via s_load
// (k,j loop indices are wave-uniform). Writes finite aggr (inf -> 0).
__global__ __launch_bounds__(256) void k_aggr(
    const int* __restrict__ node_order, const int* __restrict__ row_ptr,
    const int* __restrict__ s_src, const float* __restrict__ s_ea,
    const float* __restrict__ z,
    const float* __restrict__ w1b, const float* __restrict__ w2,
    const float* __restrict__ b2,
    float* __restrict__ aggr) {
  const int r = blockIdx.x * 256 + threadIdx.x;
  if (r >= N_NODES) return;
  const int node = node_order[r];
  const int p0 = row_ptr[node];
  const int p1 = row_ptr[node + 1];

  float mn[64];
  #pragma unroll
  for (int j = 0; j < 64; ++j) mn[j] = INFINITY;

  for (int p = p0; p < p1; ++p) {
    const int src = s_src[p];
    const float ea = s_ea[p];
    const float4* zr = reinterpret_cast<const float4*>(z + (size_t)src * HDIM);

    float m[64];
    #pragma unroll
    for (int j = 0; j < 64; ++j) m[j] = b2[j];

    for (int k4 = 0; k4 < 16; ++k4) {
      float4 zv = zr[k4];
      float hk0 = fmaxf(fmaf(ea, w1b[4*k4+0], zv.x), 0.0f);
      float hk1 = fmaxf(fmaf(ea, w1b[4*k4+1], zv.y), 0.0f);
      float hk2 = fmaxf(fmaf(ea, w1b[4*k4+2], zv.z), 0.0f);
      float hk3 = fmaxf(fmaf(ea, w1b[4*k4+3], zv.w), 0.0f);
      const float* wr0 = w2 + (4*k4+0) * 64;
      const float* wr1 = w2 + (4*k4+1) * 64;
      const float* wr2 = w2 + (4*k4+2) * 64;
      const float* wr3 = w2 + (4*k4+3) * 64;
      #pragma unroll
      for (int j = 0; j < 64; ++j) m[j] = fmaf(hk0, wr0[j], m[j]);
      #pragma unroll
      for (int j = 0; j < 64; ++j) m[j] = fmaf(hk1, wr1[j], m[j]);
      #pragma unroll
      for (int j = 0; j < 64; ++j) m[j] = fmaf(hk2, wr2[j], m[j]);
      #pragma unroll
      for (int j = 0; j < 64; ++j) m[j] = fmaf(hk3, wr3[j], m[j]);
    }
    #pragma unroll
    for (int j = 0; j < 64; ++j) mn[j] = fminf(mn[j], m[j]);
  }

  float4* ar = reinterpret_cast<float4*>(aggr + (size_t)node * HDIM);
  #pragma unroll
  for (int q = 0; q < 16; ++q) {
    float4 v;
    v.x = isinf(mn[4*q+0]) ? 0.0f : mn[4*q+0];
    v.y = isinf(mn[4*q+1]) ? 0.0f : mn[4*q+1];
    v.z = isinf(mn[4*q+2]) ? 0.0f : mn[4*q+2];
    v.w = isinf(mn[4*q+3]) ? 0.0f : mn[4*q+3];
    ar[q] = v;
  }
}

// Per node: u=[h, aggr]; h1=relu(u@U1+b1); h_new=h1@U2+b2; then
// z_next = h_new @ W1a[l+1] + b1[l+1]  (or final fc for LAST).
template <int LAST>
__global__ __launch_bounds__(256) void k_update(
    const float* __restrict__ aggr,
    const float* __restrict__ u1w, const float* __restrict__ u1b,
    const float* __restrict__ u2w, const float* __restrict__ u2b,
    const float* __restrict__ w1next, const float* __restrict__ b1next,
    const float* __restrict__ fcw, const float* __restrict__ fcb,
    float* __restrict__ h, float* __restrict__ z, float* __restrict__ out) {
  __shared__ float us[64][129];
  __shared__ float h1s[64][65];
  const int t = threadIdx.x;
  const int nl = t >> 2;
  const int l4 = t & 3;
  const int i = blockIdx.x * 64 + nl;
  const bool valid = (i < N_NODES);
  const size_t off = (size_t)(valid ? i : 0) * HDIM;
  const int jbase = l4 * 16;

  #pragma unroll
  for (int q = 0; q < 4; ++q) {
    float4 hv = reinterpret_cast<const float4*>(h + off)[l4 * 4 + q];
    us[nl][jbase + 4*q + 0] = hv.x;
    us[nl][jbase + 4*q + 1] = hv.y;
    us[nl][jbase + 4*q + 2] = hv.z;
    us[nl][jbase + 4*q + 3] = hv.w;
    float4 av = reinterpret_cast<const float4*>(aggr + off)[l4 * 4 + q];
    us[nl][64 + jbase + 4*q + 0] = av.x;
    us[nl][64 + jbase + 4*q + 1] = av.y;
    us[nl][64 + jbase + 4*q + 2] = av.z;
    us[nl][64 + jbase + 4*q + 3] = av.w;
  }
  __syncthreads();

  float acc[16];
  #pragma unroll
  for (int jj = 0; jj < 16; ++jj) acc[jj] = u1b[jbase + jj];
  #pragma unroll 4
  for (int k = 0; k < 128; ++k) {
    float uk = us[nl][k];
    const float* wr = u1w + k * 64 + jbase;
    #pragma unroll
    for (int jj = 0; jj < 16; ++jj) acc[jj] = fmaf(uk, wr[jj], acc[jj]);
  }
  #pragma unroll
  for (int jj = 0; jj < 16; ++jj) h1s[nl][jbase + jj] = fmaxf(acc[jj], 0.0f);
  __syncthreads();

  float hn[16];
  #pragma unroll
  for (int jj = 0; jj < 16; ++jj) hn[jj] = u2b[jbase + jj];
  #pragma unroll 4
  for (int k = 0; k < 64; ++k) {
    float hk = h1s[nl][k];
    const float* wr = u2w + k * 64 + jbase;
    #pragma unroll
    for (int jj = 0; jj < 16; ++jj) hn[jj] = fmaf(hk, wr[jj], hn[jj]);
  }
  if (valid) {
    #pragma unroll
    for (int q = 0; q < 4; ++q)
      reinterpret_cast<float4*>(h + off)[l4 * 4 + q] =
          make_float4(hn[4*q], hn[4*q+1], hn[4*q+2], hn[4*q+3]);
  }

  if (LAST) {
    float s = 0.0f;
    #pragma unroll
    for (int jj = 0; jj < 16; ++jj) s = fmaf(hn[jj], fcw[jbase + jj], s);
    s += __shfl_xor(s, 1);
    s += __shfl_xor(s, 2);
    if (l4 == 0 && valid) out[i] = s + fcb[0];
  } else {
    __syncthreads();
    #pragma unroll
    for (int jj = 0; jj < 16; ++jj) h1s[nl][jbase + jj] = hn[jj];
    __syncthreads();
    float zz[16];
    #pragma unroll
    for (int jj = 0; jj < 16; ++jj) zz[jj] = b1next[jbase + jj];
    #pragma unroll 4
    for (int k = 0; k < 64; ++k) {
      float hk = h1s[nl][k];
      const float* wr = w1next + k * 64 + jbase;
      #pragma unroll
      for (int jj = 0; jj < 16; ++jj) zz[jj] = fmaf(hk, wr[jj], zz[jj]);
    }
    if (valid) {
      #pragma unroll
      for (int q = 0; q < 4; ++q)
        reinterpret_cast<float4*>(z + off)[l4 * 4 + q] =
            make_float4(zz[4*q], zz[4*q+1], zz[4*q+2], zz[4*q+3]);
    }
  }
}

extern "C" void kernel_launch(void* const* d_in, const int* in_sizes, int n_in,
                              void* d_out, int out_size, void* d_ws, size_t ws_size,
                              hipStream_t stream) {
  const float* x      = (const float*)d_in[0];
  const int*   ei     = (const int*)d_in[1];
  const float* eattr  = (const float*)d_in[2];
  const float* emb_w  = (const float*)d_in[3];
  const float* emb_b  = (const float*)d_in[4];
  const float* msg_w1 = (const float*)d_in[5];
  const float* msg_b1 = (const float*)d_in[6];
  const float* msg_w2 = (const float*)d_in[7];
  const float* msg_b2 = (const float*)d_in[8];
  const float* upd_w1 = (const float*)d_in[9];
  const float* upd_b1 = (const float*)d_in[10];
  const float* upd_w2 = (const float*)d_in[11];
  const float* upd_b2 = (const float*)d_in[12];
  const float* fc_w   = (const float*)d_in[13];
  const float* fc_b   = (const float*)d_in[14];
  float* out = (float*)d_out;

  // workspace layout
  float* h     = (float*)d_ws;                          // N*64
  float* zbuf  = h + (size_t)N_NODES * HDIM;            // N*64
  float* aggr  = zbuf + (size_t)N_NODES * HDIM;         // N*64
  float* s_ea  = aggr + (size_t)N_NODES * HDIM;         // E
  int*   s_src = (int*)(s_ea + N_EDGES);                // E
  int*   row_ptr = s_src + N_EDGES;                     // N+1
  int*   node_order = row_ptr + (N_NODES + 1);          // N
  int*   deg   = node_order + N_NODES;                  // N
  int*   cursor= deg + N_NODES;                         // N
  int*   bhist = cursor + N_NODES;                      // NBUCK
  int*   bcursor = bhist + NBUCK;                       // NBUCK

  const int nodeBlocks = (N_NODES + 63) / 64;
  const int nodeBlocks256 = (N_NODES + 255) / 256;
  const int edgeBlocks = (N_EDGES + 255) / 256;
  const int zeroN = 2 * N_NODES + NBUCK;  // deg, cursor, bhist contiguous

  // ---- CSR + degree-sort build (once per launch) ----
  k_zero_int<<<(zeroN + 255) / 256, 256, 0, stream>>>(deg, zeroN);
  k_deg_count<<<edgeBlocks, 256, 0, stream>>>(ei, deg);
  k_rowptr<<<1, SCAN_T, 0, stream>>>(deg, row_ptr);
  k_scatter<<<edgeBlocks, 256, 0, stream>>>(ei, eattr, row_ptr, cursor, s_src, s_ea);
  k_bucket_hist<<<nodeBlocks256, 256, 0, stream>>>(deg, bhist);
  k_bucket_scan<<<1, 64, 0, stream>>>(bhist, bcursor);
  k_bucket_scatter<<<nodeBlocks256, 256, 0, stream>>>(deg, bcursor, node_order);

  // ---- layers ----
  k_embed_z<<<nodeBlocks, 256, 0, stream>>>(x, emb_w, emb_b, msg_w1, msg_b1, h, zbuf);

  for (int l = 0; l < 5; ++l) {
    k_aggr<<<nodeBlocks256, 256, 0, stream>>>(
        node_order, row_ptr, s_src, s_ea, zbuf,
        msg_w1 + l * 65 * 64 + 64 * 64,   // w1b: row 64 (edge_attr coeffs)
        msg_w2 + l * 64 * 64,
        msg_b2 + l * 64,
        aggr);
    if (l < 4) {
      k_update<0><<<nodeBlocks, 256, 0, stream>>>(
          aggr,
          upd_w1 + l * 128 * 64, upd_b1 + l * 64,
          upd_w2 + l * 64 * 64,  upd_b2 + l * 64,
          msg_w1 + (l + 1) * 65 * 64, msg_b1 + (l + 1) * 64,
          nullptr, nullptr,
          h, zbuf, nullptr);
    } else {
      k_update<1><<<nodeBlocks, 256, 0, stream>>>(
          aggr,
          upd_w1 + l * 128 * 64, upd_b1 + l * 64,
          upd_w2 + l * 64 * 64,  upd_b2 + l * 64,
          nullptr, nullptr,
          fc_w, fc_b,
          h, zbuf, out);
    }
  }
}

// Round 3
// 2564.756 us; speedup vs baseline: 8.9633x; 1.8208x over previous
//
#include <hip/hip_runtime.h>
#include <math.h>

#define N_NODES 100000
#define N_EDGES 1600000
#define HDIM 64
#define NBUCK 64
#define SCAN_T 1024
#define SCAN_CHUNK 98   // ceil(100000/1024)

// ---------------- CSR build ----------------

__global__ __launch_bounds__(256) void k_zero_int(int* __restrict__ p, int n) {
  int i = blockIdx.x * 256 + threadIdx.x;
  if (i < n) p[i] = 0;
}

__global__ __launch_bounds__(256) void k_deg_count(const int* __restrict__ ei,
                                                   int* __restrict__ deg) {
  int e = blockIdx.x * 256 + threadIdx.x;
  if (e < N_EDGES) atomicAdd(&deg[ei[N_EDGES + e]], 1);
}

// single-block exclusive scan of deg[N] -> row_ptr[N+1]
__global__ __launch_bounds__(SCAN_T) void k_rowptr(const int* __restrict__ deg,
                                                   int* __restrict__ row_ptr) {
  __shared__ int sums[SCAN_T];
  const int t = threadIdx.x;
  const int lo = t * SCAN_CHUNK;
  const int hi = min(lo + SCAN_CHUNK, N_NODES);
  int s = 0;
  for (int i = lo; i < hi; ++i) s += deg[i];
  sums[t] = s;
  __syncthreads();
  for (int off = 1; off < SCAN_T; off <<= 1) {
    int v = (t >= off) ? sums[t - off] : 0;
    __syncthreads();
    sums[t] += v;
    __syncthreads();
  }
  int run = (t == 0) ? 0 : sums[t - 1];
  for (int i = lo; i < hi; ++i) { row_ptr[i] = run; run += deg[i]; }
  if (t == SCAN_T - 1) row_ptr[N_NODES] = run;
}

__global__ __launch_bounds__(256) void k_scatter(
    const int* __restrict__ ei, const float* __restrict__ eattr,
    const int* __restrict__ row_ptr, int* __restrict__ cursor,
    int* __restrict__ s_src, float* __restrict__ s_ea) {
  int e = blockIdx.x * 256 + threadIdx.x;
  if (e >= N_EDGES) return;
  int d = ei[N_EDGES + e];
  int pos = row_ptr[d] + atomicAdd(&cursor[d], 1);
  s_src[pos] = ei[e];
  s_ea[pos] = eattr[e];
}

__global__ __launch_bounds__(256) void k_bucket_hist(const int* __restrict__ deg,
                                                     int* __restrict__ bhist) {
  int i = blockIdx.x * 256 + threadIdx.x;
  if (i < N_NODES) atomicAdd(&bhist[min(deg[i], NBUCK - 1)], 1);
}

__global__ __launch_bounds__(64) void k_bucket_scan(const int* __restrict__ bhist,
                                                    int* __restrict__ bcursor) {
  if (threadIdx.x == 0) {
    int run = 0;
    for (int b = 0; b < NBUCK; ++b) { bcursor[b] = run; run += bhist[b]; }
  }
}

__global__ __launch_bounds__(256) void k_bucket_scatter(const int* __restrict__ deg,
                                                        int* __restrict__ bcursor,
                                                        int* __restrict__ node_order) {
  __shared__ int lhist[NBUCK];
  __shared__ int lbase[NBUCK];
  __shared__ int lcur[NBUCK];
  const int t = threadIdx.x;
  const int i = blockIdx.x * 256 + t;
  if (t < NBUCK) { lhist[t] = 0; lcur[t] = 0; }
  __syncthreads();
  int b = -1;
  if (i < N_NODES) { b = min(deg[i], NBUCK - 1); atomicAdd(&lhist[b], 1); }
  __syncthreads();
  if (t < NBUCK && lhist[t] > 0) lbase[t] = atomicAdd(&bcursor[t], lhist[t]);
  __syncthreads();
  if (i < N_NODES) {
    int r = atomicAdd(&lcur[b], 1);
    node_order[lbase[b] + r] = i;
  }
}

// ---------------- per-layer kernels ----------------

// h = x*emb_w + emb_b (NF==1), then z = h @ W1a[0] + b1[0].
__global__ __launch_bounds__(256) void k_embed_z(
    const float* __restrict__ x, const float* __restrict__ emb_w,
    const float* __restrict__ emb_b,
    const float* __restrict__ w1, const float* __restrict__ b1,
    float* __restrict__ h, float* __restrict__ z) {
  __shared__ float hs[64][65];
  const int t = threadIdx.x;
  const int nl = t >> 2;
  const int l4 = t & 3;
  const int i = blockIdx.x * 64 + nl;
  const bool valid = (i < N_NODES);
  const int jbase = l4 * 16;
  const float xv = valid ? x[i] : 0.0f;

  float hv[16];
  #pragma unroll
  for (int jj = 0; jj < 16; ++jj) {
    int j = jbase + jj;
    hv[jj] = fmaf(xv, emb_w[j], emb_b[j]);
    hs[nl][j] = hv[jj];
  }
  if (valid) {
    #pragma unroll
    for (int q = 0; q < 4; ++q)
      reinterpret_cast<float4*>(h + (size_t)i * HDIM)[l4 * 4 + q] =
          make_float4(hv[4*q], hv[4*q+1], hv[4*q+2], hv[4*q+3]);
  }
  __syncthreads();

  float acc[16];
  #pragma unroll
  for (int jj = 0; jj < 16; ++jj) acc[jj] = b1[jbase + jj];
  #pragma unroll 8
  for (int k = 0; k < 64; ++k) {
    float hk = hs[nl][k];
    const float* wr = w1 + k * 64 + jbase;
    #pragma unroll
    for (int jj = 0; jj < 16; ++jj) acc[jj] = fmaf(hk, wr[jj], acc[jj]);
  }
  if (valid) {
    #pragma unroll
    for (int q = 0; q < 4; ++q)
      reinterpret_cast<float4*>(z + (size_t)i * HDIM)[l4 * 4 + q] =
          make_float4(acc[4*q], acc[4*q+1], acc[4*q+2], acc[4*q+3]);
  }
}

// Aggregation: block = 4 waves. Waves (0,1) -> nodes [b*128, b*128+64) halves 0/1;
// waves (2,3) -> nodes [b*128+64, b*128+128). Each thread computes 32 output cols
// for one node. Weight addresses wave-uniform -> s_load (scalar pipe).
__global__ __launch_bounds__(256) void k_aggr2(
    const int* __restrict__ node_order, const int* __restrict__ row_ptr,
    const int* __restrict__ s_src, const float* __restrict__ s_ea,
    const float* __restrict__ z,
    const float* __restrict__ w1b, const float* __restrict__ w2,
    const float* __restrict__ b2,
    float* __restrict__ aggr) {
  const int t = threadIdx.x;
  const int lane = t & 63;
  const int wv = t >> 6;
  const int half = __builtin_amdgcn_readfirstlane(wv & 1);
  const int pair = __builtin_amdgcn_readfirstlane(wv >> 1);
  const int jb = half * 32;
  const int r = blockIdx.x * 128 + pair * 64 + lane;
  if (r >= N_NODES) return;
  const int node = node_order[r];
  const int p0 = row_ptr[node];
  const int p1 = row_ptr[node + 1];

  float mn[32];
  #pragma unroll
  for (int j = 0; j < 32; ++j) mn[j] = INFINITY;

  for (int p = p0; p < p1; ++p) {
    const int src = s_src[p];
    const float ea = s_ea[p];
    const float4* zr = reinterpret_cast<const float4*>(z + (size_t)src * HDIM);

    float m[32];
    #pragma unroll
    for (int j = 0; j < 32; ++j) m[j] = b2[jb + j];

    for (int k4 = 0; k4 < 16; ++k4) {
      float4 zv = zr[k4];
      float h0 = fmaxf(fmaf(ea, w1b[4*k4+0], zv.x), 0.0f);
      float h1 = fmaxf(fmaf(ea, w1b[4*k4+1], zv.y), 0.0f);
      float h2 = fmaxf(fmaf(ea, w1b[4*k4+2], zv.z), 0.0f);
      float h3 = fmaxf(fmaf(ea, w1b[4*k4+3], zv.w), 0.0f);
      const float* wr0 = w2 + (4*k4+0) * 64 + jb;
      const float* wr1 = w2 + (4*k4+1) * 64 + jb;
      const float* wr2 = w2 + (4*k4+2) * 64 + jb;
      const float* wr3 = w2 + (4*k4+3) * 64 + jb;
      #pragma unroll
      for (int j = 0; j < 32; ++j) m[j] = fmaf(h0, wr0[j], m[j]);
      #pragma unroll
      for (int j = 0; j < 32; ++j) m[j] = fmaf(h1, wr1[j], m[j]);
      #pragma unroll
      for (int j = 0; j < 32; ++j) m[j] = fmaf(h2, wr2[j], m[j]);
      #pragma unroll
      for (int j = 0; j < 32; ++j) m[j] = fmaf(h3, wr3[j], m[j]);
    }
    #pragma unroll
    for (int j = 0; j < 32; ++j) mn[j] = fminf(mn[j], m[j]);
  }

  float4* ar = reinterpret_cast<float4*>(aggr + (size_t)node * HDIM + jb);
  #pragma unroll
  for (int q = 0; q < 8; ++q) {
    float4 v;
    v.x = isinf(mn[4*q+0]) ? 0.0f : mn[4*q+0];
    v.y = isinf(mn[4*q+1]) ? 0.0f : mn[4*q+1];
    v.z = isinf(mn[4*q+2]) ? 0.0f : mn[4*q+2];
    v.w = isinf(mn[4*q+3]) ? 0.0f : mn[4*q+3];
    ar[q] = v;
  }
}

// Update: same wave-pair structure. u = [h, aggr] streamed from global;
// weights via s_load; h1/hn exchanged through one LDS buffer (stride 65,
// 2-way-free banks). In-place h update is safe: each block touches only
// its own 128 rows.
template <int LAST>
__global__ __launch_bounds__(256) void k_update2(
    const float* __restrict__ aggr,
    const float* __restrict__ u1w, const float* __restrict__ u1b,
    const float* __restrict__ u2w, const float* __restrict__ u2b,
    const float* __restrict__ w1next, const float* __restrict__ b1next,
    const float* __restrict__ fcw, const float* __restrict__ fcb,
    float* __restrict__ h, float* __restrict__ z, float* __restrict__ out) {
  __shared__ float h1s[128][65];
  const int t = threadIdx.x;
  const int lane = t & 63;
  const int wv = t >> 6;
  const int half = __builtin_amdgcn_readfirstlane(wv & 1);
  const int pair = __builtin_amdgcn_readfirstlane(wv >> 1);
  const int jb = half * 32;
  const int nl = pair * 64 + lane;            // 0..127
  const int node = blockIdx.x * 128 + nl;
  const bool valid = (node < N_NODES);
  const size_t off = (size_t)(valid ? node : 0) * HDIM;

  // ---- phase 1: acc[32] = (u @ U1 + b1)[jb..jb+32), u = [h, aggr] ----
  float acc[32];
  #pragma unroll
  for (int j = 0; j < 32; ++j) acc[j] = u1b[jb + j];
  {
    const float4* hr = reinterpret_cast<const float4*>(h + off);
    for (int k4 = 0; k4 < 16; ++k4) {
      float4 uv = hr[k4];
      const float* w0 = u1w + (4*k4+0) * 64 + jb;
      const float* w1 = u1w + (4*k4+1) * 64 + jb;
      const float* w2 = u1w + (4*k4+2) * 64 + jb;
      const float* w3 = u1w + (4*k4+3) * 64 + jb;
      #pragma unroll
      for (int j = 0; j < 32; ++j) acc[j] = fmaf(uv.x, w0[j], acc[j]);
      #pragma unroll
      for (int j = 0; j < 32; ++j) acc[j] = fmaf(uv.y, w1[j], acc[j]);
      #pragma unroll
      for (int j = 0; j < 32; ++j) acc[j] = fmaf(uv.z, w2[j], acc[j]);
      #pragma unroll
      for (int j = 0; j < 32; ++j) acc[j] = fmaf(uv.w, w3[j], acc[j]);
    }
    const float4* ar = reinterpret_cast<const float4*>(aggr + off);
    for (int k4 = 0; k4 < 16; ++k4) {
      float4 uv = ar[k4];
      const float* w0 = u1w + (64 + 4*k4+0) * 64 + jb;
      const float* w1 = u1w + (64 + 4*k4+1) * 64 + jb;
      const float* w2 = u1w + (64 + 4*k4+2) * 64 + jb;
      const float* w3 = u1w + (64 + 4*k4+3) * 64 + jb;
      #pragma unroll
      for (int j = 0; j < 32; ++j) acc[j] = fmaf(uv.x, w0[j], acc[j]);
      #pragma unroll
      for (int j = 0; j < 32; ++j) acc[j] = fmaf(uv.y, w1[j], acc[j]);
      #pragma unroll
      for (int j = 0; j < 32; ++j) acc[j] = fmaf(uv.z, w2[j], acc[j]);
      #pragma unroll
      for (int j = 0; j < 32; ++j) acc[j] = fmaf(uv.w, w3[j], acc[j]);
    }
  }
  #pragma unroll
  for (int j = 0; j < 32; ++j) h1s[nl][jb + j] = fmaxf(acc[j], 0.0f);
  __syncthreads();

  // ---- phase 2: hn[32] = (relu(h1) @ U2 + b2)[jb..jb+32) ----
  float hn[32];
  #pragma unroll
  for (int j = 0; j < 32; ++j) hn[j] = u2b[jb + j];
  for (int k = 0; k < 64; ++k) {
    float hk = h1s[nl][k];
    const float* wr = u2w + k * 64 + jb;
    #pragma unroll
    for (int j = 0; j < 32; ++j) hn[j] = fmaf(hk, wr[j], hn[j]);
  }
  if (valid) {
    #pragma unroll
    for (int q = 0; q < 8; ++q)
      reinterpret_cast<float4*>(h + off)[half * 8 + q] =
          make_float4(hn[4*q], hn[4*q+1], hn[4*q+2], hn[4*q+3]);
  }

  if (LAST) {
    float s = 0.0f;
    #pragma unroll
    for (int j = 0; j < 32; ++j) s = fmaf(hn[j], fcw[jb + j], s);
    __syncthreads();
    if (half) h1s[nl][64] = s;
    __syncthreads();
    if (!half && valid) out[node] = s + h1s[nl][64] + fcb[0];
  } else {
    __syncthreads();   // all phase-2 LDS reads done before overwrite
    #pragma unroll
    for (int j = 0; j < 32; ++j) h1s[nl][jb + j] = hn[j];
    __syncthreads();
    // ---- phase 3: z = hn @ W1a_next + b1_next ----
    float zz[32];
    #pragma unroll
    for (int j = 0; j < 32; ++j) zz[j] = b1next[jb + j];
    for (int k = 0; k < 64; ++k) {
      float hk = h1s[nl][k];
      const float* wr = w1next + k * 64 + jb;
      #pragma unroll
      for (int j = 0; j < 32; ++j) zz[j] = fmaf(hk, wr[j], zz[j]);
    }
    if (valid) {
      #pragma unroll
      for (int q = 0; q < 8; ++q)
        reinterpret_cast<float4*>(z + off)[half * 8 + q] =
            make_float4(zz[4*q], zz[4*q+1], zz[4*q+2], zz[4*q+3]);
    }
  }
}

extern "C" void kernel_launch(void* const* d_in, const int* in_sizes, int n_in,
                              void* d_out, int out_size, void* d_ws, size_t ws_size,
                              hipStream_t stream) {
  const float* x      = (const float*)d_in[0];
  const int*   ei     = (const int*)d_in[1];
  const float* eattr  = (const float*)d_in[2];
  const float* emb_w  = (const float*)d_in[3];
  const float* emb_b  = (const float*)d_in[4];
  const float* msg_w1 = (const float*)d_in[5];
  const float* msg_b1 = (const float*)d_in[6];
  const float* msg_w2 = (const float*)d_in[7];
  const float* msg_b2 = (const float*)d_in[8];
  const float* upd_w1 = (const float*)d_in[9];
  const float* upd_b1 = (const float*)d_in[10];
  const float* upd_w2 = (const float*)d_in[11];
  const float* upd_b2 = (const float*)d_in[12];
  const float* fc_w   = (const float*)d_in[13];
  const float* fc_b   = (const float*)d_in[14];
  float* out = (float*)d_out;

  // workspace layout
  float* h     = (float*)d_ws;                          // N*64
  float* zbuf  = h + (size_t)N_NODES * HDIM;            // N*64
  float* aggr  = zbuf + (size_t)N_NODES * HDIM;         // N*64
  float* s_ea  = aggr + (size_t)N_NODES * HDIM;         // E
  int*   s_src = (int*)(s_ea + N_EDGES);                // E
  int*   row_ptr = s_src + N_EDGES;                     // N+1
  int*   node_order = row_ptr + (N_NODES + 1);          // N
  int*   deg   = node_order + N_NODES;                  // N
  int*   cursor= deg + N_NODES;                         // N
  int*   bhist = cursor + N_NODES;                      // NBUCK
  int*   bcursor = bhist + NBUCK;                       // NBUCK

  const int nodeBlocks64 = (N_NODES + 63) / 64;
  const int nodeBlocks128 = (N_NODES + 127) / 128;
  const int nodeBlocks256 = (N_NODES + 255) / 256;
  const int edgeBlocks = (N_EDGES + 255) / 256;
  const int zeroN = 2 * N_NODES + NBUCK;  // deg, cursor, bhist contiguous

  // ---- CSR + degree-sort build (once per launch) ----
  k_zero_int<<<(zeroN + 255) / 256, 256, 0, stream>>>(deg, zeroN);
  k_deg_count<<<edgeBlocks, 256, 0, stream>>>(ei, deg);
  k_rowptr<<<1, SCAN_T, 0, stream>>>(deg, row_ptr);
  k_scatter<<<edgeBlocks, 256, 0, stream>>>(ei, eattr, row_ptr, cursor, s_src, s_ea);
  k_bucket_hist<<<nodeBlocks256, 256, 0, stream>>>(deg, bhist);
  k_bucket_scan<<<1, 64, 0, stream>>>(bhist, bcursor);
  k_bucket_scatter<<<nodeBlocks256, 256, 0, stream>>>(deg, bcursor, node_order);

  // ---- layers ----
  k_embed_z<<<nodeBlocks64, 256, 0, stream>>>(x, emb_w, emb_b, msg_w1, msg_b1, h, zbuf);

  for (int l = 0; l < 5; ++l) {
    k_aggr2<<<nodeBlocks128, 256, 0, stream>>>(
        node_order, row_ptr, s_src, s_ea, zbuf,
        msg_w1 + l * 65 * 64 + 64 * 64,   // w1b: row 64 (edge_attr coeffs)
        msg_w2 + l * 64 * 64,
        msg_b2 + l * 64,
        aggr);
    if (l < 4) {
      k_update2<0><<<nodeBlocks128, 256, 0, stream>>>(
          aggr,
          upd_w1 + l * 128 * 64, upd_b1 + l * 64,
          upd_w2 + l * 64 * 64,  upd_b2 + l * 64,
          msg_w1 + (l + 1) * 65 * 64, msg_b1 + (l + 1) * 64,
          nullptr, nullptr,
          h, zbuf, nullptr);
    } else {
      k_update2<1><<<nodeBlocks128, 256, 0, stream>>>(
          aggr,
          upd_w1 + l * 128 * 64, upd_b1 + l * 64,
          upd_w2 + l * 64 * 64,  upd_b2 + l * 64,
          nullptr, nullptr,
          fc_w, fc_b,
          h, zbuf, out);
    }
  }
}